// Round 3
// baseline (337.860 us; speedup 1.0000x reference)
//
#include <hip/hip_runtime.h>
#include <hip/hip_bf16.h>

typedef __bf16 bf16_t;
typedef __attribute__((ext_vector_type(8))) __bf16 bf16x8;
typedef __attribute__((ext_vector_type(4))) float f32x4;

#define E_DIM 256
#define J_DIM 32
#define B_DIM 4096
#define M_DIM (B_DIM * J_DIM)
#define BM 64
#define BK 32
#define LDA 40   // bf16: BK + 8 pad (16B-aligned, spreads banks)
#define LDB 40
#define LDAF 33  // fp32: BK + 1 pad (max 2-way bank alias = free)

// load 8 consecutive fp32, convert to bf16x8 (RNE)
__device__ inline bf16x8 cvt8(const float* __restrict__ p) {
    f32x4 a = *(const f32x4*)p;
    f32x4 b = *(const f32x4*)(p + 4);
    bf16x8 r;
    r[0] = (bf16_t)a[0]; r[1] = (bf16_t)a[1]; r[2] = (bf16_t)a[2]; r[3] = (bf16_t)a[3];
    r[4] = (bf16_t)b[0]; r[5] = (bf16_t)b[1]; r[6] = (bf16_t)b[2]; r[7] = (bf16_t)b[3];
    return r;
}

// vkb[j][f] = bias[f] + sum_e V[f,e]*keys[j,e]   (fp32 VALU, tiny)
__global__ __launch_bounds__(256) void vkb_kernel(const float* __restrict__ keys,
                                                  const float* __restrict__ V,
                                                  const float* __restrict__ bias,
                                                  float* __restrict__ vkb) {
    int j = blockIdx.x, f = threadIdx.x;
    __shared__ float sk[E_DIM];
    sk[f] = keys[j * E_DIM + f];
    __syncthreads();
    float acc = bias[f];
    for (int e = 0; e < E_DIM; e += 4) {
        f32x4 vv = *(const f32x4*)(V + (size_t)f * E_DIM + e);
#pragma unroll
        for (int i = 0; i < 4; ++i) acc += vv[i] * sk[e + i];
    }
    vkb[(size_t)j * E_DIM + f] = acc;
}

// xk[b][j] = sum_e x[b,e]*keys[j,e]; 8 b's per block (fp32 VALU)
__global__ __launch_bounds__(256) void xk_kernel(const float* __restrict__ x,
                                                 const float* __restrict__ keys,
                                                 float* __restrict__ xk) {
    __shared__ __align__(16) float sK[J_DIM][E_DIM];
    __shared__ __align__(16) float sX[8][E_DIM];
    int tid = threadIdx.x;
    int b0 = blockIdx.x * 8;
#pragma unroll
    for (int it = 0; it < 8; ++it) {
        int t = it * 256 + tid;
        *(f32x4*)(&sK[0][0] + (size_t)t * 4) = *(const f32x4*)(keys + (size_t)t * 4);
    }
#pragma unroll
    for (int it = 0; it < 2; ++it) {
        int t = it * 256 + tid;
        *(f32x4*)(&sX[0][0] + (size_t)t * 4) =
            *(const f32x4*)(x + (size_t)b0 * E_DIM + (size_t)t * 4);
    }
    __syncthreads();
    int j = tid & 31, bl = tid >> 5;
    float acc = 0.f;
    for (int e = 0; e < E_DIM; e += 4) {
        f32x4 xv = *(const f32x4*)(&sX[bl][e]);
        f32x4 kv = *(const f32x4*)(&sK[j][e]);
#pragma unroll
        for (int i = 0; i < 4; ++i) acc += xv[i] * kv[i];
    }
    xk[(size_t)(b0 + bl) * J_DIM + j] = acc;
}

// wx[b][f] = sum_e W[f,e]*x[b,e]  (MFMA bf16, BM=64 rows/block)
__global__ __launch_bounds__(256) void wx_kernel(const float* __restrict__ x,
                                                 const float* __restrict__ W,
                                                 float* __restrict__ wx) {
    __shared__ __align__(16) bf16_t sA[BM][LDA];
    __shared__ __align__(16) bf16_t sB[E_DIM][LDB];
    int tid = threadIdx.x;
    int w = tid >> 6, lane = tid & 63, quad = lane >> 4, l15 = lane & 15;
    int m0 = blockIdx.x * BM;
    f32x4 acc[16];
#pragma unroll
    for (int nt = 0; nt < 16; ++nt)
#pragma unroll
        for (int r = 0; r < 4; ++r) acc[nt][r] = 0.f;
    int arow = tid >> 2, akk = (tid & 3) * 8;
    for (int kc = 0; kc < 8; ++kc) {
        int k0 = kc * BK;
        __syncthreads();
        *(bf16x8*)(&sA[arow][akk]) = cvt8(x + (size_t)(m0 + arow) * E_DIM + k0 + akk);
#pragma unroll
        for (int it = 0; it < 4; ++it) {
            int t = it * 256 + tid;
            int n = t >> 2, kk = (t & 3) * 8;
            *(bf16x8*)(&sB[n][kk]) = cvt8(W + (size_t)n * E_DIM + k0 + kk);
        }
        __syncthreads();
        bf16x8 af = *(const bf16x8*)(&sA[w * 16 + l15][quad * 8]);
#pragma unroll
        for (int nt = 0; nt < 16; ++nt) {
            bf16x8 bfr = *(const bf16x8*)(&sB[nt * 16 + l15][quad * 8]);
            acc[nt] = __builtin_amdgcn_mfma_f32_16x16x32_bf16(af, bfr, acc[nt], 0, 0, 0);
        }
    }
#pragma unroll
    for (int nt = 0; nt < 16; ++nt)
#pragma unroll
        for (int r = 0; r < 4; ++r)
            wx[(size_t)(m0 + w * 16 + quad * 4 + r) * E_DIM + nt * 16 + l15] = acc[nt][r];
}

// main: cand = s@U^T + wx[b] + vkb[j]; gate = sigmoid(<x,s>+xk); out = normalize(s+gate*relu(cand))
// gate dot is computed in FP32 (bf16 rounding of <x,s> was the dominant error).
__global__ __launch_bounds__(256) void memcell_kernel(
    const float* __restrict__ x, const float* __restrict__ state,
    const float* __restrict__ U, const float* __restrict__ wx,
    const float* __restrict__ xk, const float* __restrict__ vkb,
    float* __restrict__ out) {
    __shared__ __align__(16) bf16_t sA[BM][LDA];
    __shared__ __align__(16) bf16_t sB[E_DIM][LDB];
    __shared__ __align__(16) bf16_t sX[2][E_DIM];
    __shared__ __align__(16) float sAf[BM][LDAF];   // fp32 state tile (gate dot)
    __shared__ __align__(16) float sXf[2][E_DIM];   // fp32 x rows     (gate dot)
    int tid = threadIdx.x;
    int w = tid >> 6, lane = tid & 63, quad = lane >> 4, l15 = lane & 15;
    int m0 = blockIdx.x * BM;
    int b0 = m0 >> 5;                       // block covers b0, b0+1
    f32x4 acc[16];
#pragma unroll
    for (int nt = 0; nt < 16; ++nt)
#pragma unroll
        for (int r = 0; r < 4; ++r) acc[nt][r] = 0.f;
    float gdot = 0.f;
    if (tid < 64) {                          // stage the 2 x-rows (fp32 + bf16)
        int bb = tid >> 5, p = tid & 31;
        f32x4 xa = *(const f32x4*)(x + (size_t)(b0 + bb) * E_DIM + p * 8);
        f32x4 xb = *(const f32x4*)(x + (size_t)(b0 + bb) * E_DIM + p * 8 + 4);
        *(f32x4*)(&sXf[bb][p * 8]) = xa;
        *(f32x4*)(&sXf[bb][p * 8 + 4]) = xb;
        bf16x8 r;
        r[0] = (bf16_t)xa[0]; r[1] = (bf16_t)xa[1]; r[2] = (bf16_t)xa[2]; r[3] = (bf16_t)xa[3];
        r[4] = (bf16_t)xb[0]; r[5] = (bf16_t)xb[1]; r[6] = (bf16_t)xb[2]; r[7] = (bf16_t)xb[3];
        *(bf16x8*)(&sX[bb][p * 8]) = r;
    }
    int arow = tid >> 2, akk = (tid & 3) * 8;
    for (int kc = 0; kc < 8; ++kc) {
        int k0 = kc * BK;
        __syncthreads();
        {   // stage state tile: fp32 copy for gate dot + bf16 for MFMA
            const float* sp = state + (size_t)(m0 + arow) * E_DIM + k0 + akk;
            f32x4 a = *(const f32x4*)sp;
            f32x4 b = *(const f32x4*)(sp + 4);
            *(f32x4*)(&sAf[arow][akk]) = a;
            *(f32x4*)(&sAf[arow][akk + 4]) = b;
            bf16x8 r;
            r[0] = (bf16_t)a[0]; r[1] = (bf16_t)a[1]; r[2] = (bf16_t)a[2]; r[3] = (bf16_t)a[3];
            r[4] = (bf16_t)b[0]; r[5] = (bf16_t)b[1]; r[6] = (bf16_t)b[2]; r[7] = (bf16_t)b[3];
            *(bf16x8*)(&sA[arow][akk]) = r;
        }
#pragma unroll
        for (int it = 0; it < 4; ++it) {
            int t = it * 256 + tid;
            int n = t >> 2, kk = (t & 3) * 8;
            *(bf16x8*)(&sB[n][kk]) = cvt8(U + (size_t)n * E_DIM + k0 + kk);
        }
        __syncthreads();
        // A-frag: row = w*16+l15 (wave owns 16 full rows), k = k0 + quad*8 + j
        bf16x8 af = *(const bf16x8*)(&sA[w * 16 + l15][quad * 8]);
#pragma unroll
        for (int i = 0; i < 8; ++i)
            gdot += sAf[w * 16 + l15][quad * 8 + i] * sXf[w >> 1][k0 + quad * 8 + i];
#pragma unroll
        for (int nt = 0; nt < 16; ++nt) {
            bf16x8 bfr = *(const bf16x8*)(&sB[nt * 16 + l15][quad * 8]);
            acc[nt] = __builtin_amdgcn_mfma_f32_16x16x32_bf16(af, bfr, acc[nt], 0, 0, 0);
        }
    }
    // reduce gate dot across quads (k was split quad-wise): lanes sharing l15
    gdot += __shfl_xor(gdot, 16);
    gdot += __shfl_xor(gdot, 32);
    int bw = b0 + (w >> 1);                 // one b per wave
    float garg = gdot + xk[(size_t)bw * J_DIM + (w & 1) * 16 + l15];
    float gv = 1.f / (1.f + expf(-garg));
    float gate[4];
#pragma unroll
    for (int r = 0; r < 4; ++r) gate[r] = __shfl(gv, quad * 4 + r);
    // epilogue: C/D layout row = quad*4+r, col = nt*16+l15
    float sumsq[4] = {0.f, 0.f, 0.f, 0.f};
    const float* wxrow = wx + (size_t)bw * E_DIM;
#pragma unroll
    for (int nt = 0; nt < 16; ++nt) {
        int f = nt * 16 + l15;
        float wxf = wxrow[f];
#pragma unroll
        for (int r = 0; r < 4; ++r) {
            int rl = quad * 4 + r;
            int jidx = (w & 1) * 16 + rl;
            float c = acc[nt][r] + wxf + vkb[(size_t)jidx * E_DIM + f];
            c = fmaxf(c, 0.f);
            float sv = state[(size_t)(m0 + w * 16 + rl) * E_DIM + f]; // L2-hot re-read
            float t = fmaf(gate[r], c, sv);
            acc[nt][r] = t;
            sumsq[r] += t * t;
        }
    }
    float rn[4];
#pragma unroll
    for (int r = 0; r < 4; ++r) {
        float s2 = sumsq[r];
        s2 += __shfl_xor(s2, 1);
        s2 += __shfl_xor(s2, 2);
        s2 += __shfl_xor(s2, 4);
        s2 += __shfl_xor(s2, 8);
        rn[r] = 1.f / (sqrtf(s2) + 1e-8f);
    }
#pragma unroll
    for (int nt = 0; nt < 16; ++nt)
#pragma unroll
        for (int r = 0; r < 4; ++r)
            out[(size_t)(m0 + w * 16 + quad * 4 + r) * E_DIM + nt * 16 + l15] =
                acc[nt][r] * rn[r];
}

extern "C" void kernel_launch(void* const* d_in, const int* in_sizes, int n_in,
                              void* d_out, int out_size, void* d_ws, size_t ws_size,
                              hipStream_t stream) {
    const float* x     = (const float*)d_in[0];
    const float* state = (const float*)d_in[1];
    const float* keys  = (const float*)d_in[2];
    const float* U     = (const float*)d_in[3];
    const float* V     = (const float*)d_in[4];
    const float* W     = (const float*)d_in[5];
    const float* bias  = (const float*)d_in[6];
    float* out = (float*)d_out;

    float* wsf = (float*)d_ws;
    float* wx  = wsf;                                   // 4096*256 fp32 = 4 MB
    float* xk  = wsf + (size_t)B_DIM * E_DIM;           // 4096*32  fp32 = 512 KB
    float* vkb = xk + (size_t)B_DIM * J_DIM;            // 32*256   fp32 = 32 KB

    vkb_kernel<<<J_DIM, 256, 0, stream>>>(keys, V, bias, vkb);
    xk_kernel<<<B_DIM / 8, 256, 0, stream>>>(x, keys, xk);
    wx_kernel<<<B_DIM / BM, 256, 0, stream>>>(x, W, wx);
    memcell_kernel<<<M_DIM / BM, 256, 0, stream>>>(x, state, U, wx, xk, vkb, out);
}